// Round 9
// baseline (124.745 us; speedup 1.0000x reference)
//
#include <hip/hip_runtime.h>

// TsSub: out[b, p, t] = x[b, I[p], t*10] - x[b, J[p], t*10]
// x: (256, 64, 2000) f32, out: (256, 2016, 200) f32, (I,J)=triu_indices(64,k=1)
//
// Fused, combo-split with G=32, 4 balanced combos per b:
//   c0: diag rows 0..31   (496 pairs, stage 32 rows)
//   c1: diag rows 32..63  (496 pairs, stage 32 rows)
//   c2: i in 0..15  x j in 32..63 (512 pairs, stage 48 rows)
//   c3: i in 16..31 x j in 32..63 (512 pairs, stage 48 rows)
// Stage loads only sample-bearing vec4s (m=5u or 5u+2 -> .x/.z). LDS rows
// unpadded (stride 50 vec4; all LDS access is lane-sequential -> no
// conflicts). 40.4 KB LDS -> 4 blocks/CU; 1024 blocks, XCD-chunk swizzle.

#define NF      64
#define T_OUT   200
#define NPAIR   2016
#define NB      256
#define RF4     500             // vec4 per x row
#define TV4     50              // vec4 per out row
#define NCOMBO  4
#define NWG     (NB * NCOMBO)   // 1024
#define MAXROWS 48
#define MAXP    512

typedef float fx4 __attribute__((ext_vector_type(4)));

__global__ __launch_bounds__(256)
void ts_sub_g32(const fx4* __restrict__ xv, fx4* __restrict__ out) {
    __shared__ __attribute__((aligned(16))) float sf[MAXROWS * T_OUT]; // 38.4 KB
    __shared__ unsigned short ij[MAXP];     // ir | (jr<<8)
    __shared__ unsigned short ob[MAXP];     // output row index (<2016)

    const int tid = threadIdx.x;
    // bijective XCD-chunk swizzle (1024 % 8 == 0): same-b combos contiguous
    const int n   = blockIdx.x;
    const int blk = (n & 7) * (NWG / 8) + (n >> 3);
    const int b     = blk >> 2;
    const int combo = blk & 3;
    const bool diag  = combo < 2;
    const int nrows  = diag ? 32 : 48;
    const int npairs = diag ? 496 : 512;

    // --- pair tables (2 iters/thread) ---
    for (int p = tid; p < npairs; p += 256) {
        int il, jl, i, j, ir, jr;
        if (diag) {
            il = 0;                               // base32(i) = i*(63-i)/2
            while ((il + 1) * (62 - il) / 2 <= p) ++il;
            jl = p - il * (63 - il) / 2 + il + 1;
            ir = il; jr = jl;
            i = il + (combo == 1 ? 32 : 0);
            j = jl + (combo == 1 ? 32 : 0);
        } else {
            il = p >> 5; jl = p & 31;             // il 0..15, jl 0..31
            ir = il; jr = 16 + jl;
            i = il + (combo == 3 ? 16 : 0);
            j = 32 + jl;
        }
        ij[p] = (unsigned short)(ir | (jr << 8));
        ob[p] = (unsigned short)(i * (127 - i) / 2 + (j - i - 1));
    }

    // --- stage sampled rows directly from x ---
    // k in [0,200): u=k>>1, par=k&1, m=5u+2par, sample = par ? .z : .x
    {
        const fx4* __restrict__ xb = xv + (size_t)b * (NF * RF4);
        const int total = nrows * T_OUT;         // 6400 or 9600
        int slot = 0;
        int k = tid;
        if (k >= T_OUT) { slot = 1; k -= T_OUT; }   // tid < 256 < 400
        for (int idx = tid; idx < total; idx += 256) {
            int f;
            if (combo == 0)      f = slot;
            else if (combo == 1) f = slot + 32;
            else if (combo == 2) f = (slot < 16) ? slot : slot + 16;
            else                 f = slot + 16;
            int u = k >> 1, par = k & 1;
            fx4 v = xb[f * RF4 + 5 * u + 2 * par];
            sf[slot * T_OUT + k] = par ? v.z : v.x;
            slot += 1;                            // 256 = 1*200 + 56
            k += 56;
            if (k >= T_OUT) { k -= T_OUT; ++slot; }
        }
    }
    __syncthreads();

    // --- emit pair rows: incremental (slot,t4), step 256 = 5*50 + 6 ---
    const fx4* __restrict__ s4 = reinterpret_cast<const fx4*>(sf); // row stride 50
    fx4* __restrict__ obp = out + (size_t)b * (NPAIR * TV4);
    const int total = npairs * TV4;               // 24800 or 25600
    int v    = tid;
    int slot = v / TV4;
    int t4   = v - slot * TV4;
    while (v < total) {
        unsigned int e = ij[slot];
        fx4 a = s4[(e & 255u) * TV4 + t4];
        fx4 c = s4[(e >> 8) * TV4 + t4];
        fx4 r = a - c;
        __builtin_nontemporal_store(r, &obp[(size_t)ob[slot] * TV4 + t4]);
        v += 256;
        slot += 5;
        t4 += 6;
        if (t4 >= TV4) { t4 -= TV4; ++slot; }
    }
}

extern "C" void kernel_launch(void* const* d_in, const int* in_sizes, int n_in,
                              void* d_out, int out_size, void* d_ws, size_t ws_size,
                              hipStream_t stream) {
    const float* x = (const float*)d_in[0];
    float* out = (float*)d_out;
    ts_sub_g32<<<dim3(NWG), dim3(256), 0, stream>>>(
        (const fx4*)x, (fx4*)out);
}

// Round 10
// 110.273 us; speedup vs baseline: 1.1312x; 1.1312x over previous
//
#include <hip/hip_runtime.h>

// TsSub: out[b, p, t] = x[b, I[p], t*10] - x[b, J[p], t*10]
// x: (256, 64, 2000) f32, out: (256, 2016, 200) f32, (I,J)=triu_indices(64,k=1)
//
// Two kernels, XCD-matched producer/consumer (XCD = blockIdx%8 round-robin
// model; batch b owned by XCD b>>5):
//  K1: samp[b,f,k] = x[b,f,10k] into d_ws. nt vec4 loads (don't pollute L2),
//      cached stores (samp slice 1.6MB/XCD stays L2-resident).
//  K2: out[b,p,:] = samp[b,I[p],:] - samp[b,J[p],:] straight from L2
//      (no LDS staging), nt stores. 8 blocks/CU, 100% occupancy.

#define NF     64
#define T_OUT  200
#define NPAIR  2016
#define NB     256
#define RF4    500     // vec4 per x row
#define TV4    50      // vec4 per out/samp row
#define PPB    252     // output pair-rows per K2 block (2016 = 8*252)

typedef float fx4 __attribute__((ext_vector_type(4)));

// ---- K1: gather. 2048 blocks: n -> c=n&7, l=n>>3, b=32c+(l>>3), r=l&7 ----
__global__ __launch_bounds__(256)
void gather_k(const fx4* __restrict__ xv, float* __restrict__ samp) {
    const int n = blockIdx.x;
    const int c = n & 7;
    const int l = n >> 3;
    const int b = c * 32 + (l >> 3);
    const int r = l & 7;
    const int grow0 = b * NF + r * 8;        // 8 x-rows per block

    // 1600 samples; k in [0,200): vec4 m = 5*(k>>1)+2*(k&1), comp .x/.z
    int idx = threadIdx.x;
    int row = 0;
    int k   = idx;
    if (k >= T_OUT) { row = 1; k -= T_OUT; }    // tid < 256 < 400
    while (idx < 8 * T_OUT) {
        const fx4* __restrict__ src = xv + (size_t)(grow0 + row) * RF4;
        fx4 v = __builtin_nontemporal_load(&src[5 * (k >> 1) + 2 * (k & 1)]);
        samp[(size_t)(grow0 + row) * T_OUT + k] = (k & 1) ? v.z : v.x;
        idx += 256;                             // 256 = 1*200 + 56
        row += 1;
        k += 56;
        if (k >= T_OUT) { k -= T_OUT; ++row; }
    }
}

// ---- K2: pair-sub. 2048 blocks: n -> c=n&7, l=n>>3, b=32c+(l>>3), sub=l&7 ----
__global__ __launch_bounds__(256)
void pairsub_k(const float* __restrict__ samp, fx4* __restrict__ out) {
    __shared__ unsigned char pi[256];
    __shared__ unsigned char pj[256];

    const int n = blockIdx.x;
    const int c = n & 7;
    const int l = n >> 3;
    const int b   = c * 32 + (l >> 3);
    const int sub = l & 7;
    const int p0  = sub * PPB;

    {   // pair table for p in [p0, p0+252), one entry per thread
        int p = p0 + threadIdx.x;
        if (p > NPAIR - 1) p = NPAIR - 1;
        float d = 16129.0f - 8.0f * (float)p;          // 127^2 - 8p
        int i = (int)((127.0f - sqrtf(d)) * 0.5f);
        if (i < 0) i = 0;
        while (i > 0 && (i * (127 - i)) / 2 > p) --i;
        while (((i + 1) * (126 - i)) / 2 <= p) ++i;
        pi[threadIdx.x] = (unsigned char)i;
        pj[threadIdx.x] = (unsigned char)(p - (i * (127 - i)) / 2 + i + 1);
    }
    __syncthreads();

    const fx4* __restrict__ s4 =
        reinterpret_cast<const fx4*>(samp + (size_t)b * (NF * T_OUT));
    fx4* __restrict__ ob = out + ((size_t)b * NPAIR + p0) * TV4;

    // 252 rows x 50 vec4 = 12600; incremental (lp,t4), step 256 = 5*50+6
    int v  = threadIdx.x;
    int lp = v / TV4;
    int t4 = v - lp * TV4;
    while (v < PPB * TV4) {
        fx4 a  = s4[pi[lp] * TV4 + t4];
        fx4 cc = s4[pj[lp] * TV4 + t4];
        fx4 rr = a - cc;
        __builtin_nontemporal_store(rr, &ob[(size_t)lp * TV4 + t4]);
        v += 256;
        lp += 5;
        t4 += 6;
        if (t4 >= TV4) { t4 -= TV4; ++lp; }
    }
}

extern "C" void kernel_launch(void* const* d_in, const int* in_sizes, int n_in,
                              void* d_out, int out_size, void* d_ws, size_t ws_size,
                              hipStream_t stream) {
    const float* x = (const float*)d_in[0];
    float* out = (float*)d_out;
    float* samp = (float*)d_ws;      // 13,107,200 B

    gather_k<<<dim3(2048), dim3(256), 0, stream>>>((const fx4*)x, samp);
    pairsub_k<<<dim3(2048), dim3(256), 0, stream>>>(samp, (fx4*)out);
}